// Round 14
// baseline (571.737 us; speedup 1.0000x reference)
//
#include <hip/hip_runtime.h>
#include <stdint.h>

#define DD 128
#define NB_G 2048   // k_gather blocks
#define GE   1024   // k_edge persistent blocks (512 threads each)

using f32x4  = __attribute__((ext_vector_type(4))) float;
using bf16x8 = __attribute__((ext_vector_type(8))) short;

__device__ __forceinline__ float bf2f(short u) {
  union { unsigned int i; float f; } c;
  c.i = ((unsigned int)(unsigned short)u) << 16;
  return c.f;
}
__device__ __forceinline__ short f2bf(float f) {
  union { float f; unsigned int i; } c;
  c.f = f;
  unsigned int u = c.i;
  u += 0x7fffu + ((u >> 16) & 1u);
  return (short)(u >> 16);
}

// ---------------- prep: weight convert+transpose (blocks 0-4) + zero deg (blocks 5+) --------
__global__ __launch_bounds__(256) void k_prep(
    const float* __restrict__ WA, const float* __restrict__ WB, const float* __restrict__ WC,
    const float* __restrict__ WD, const float* __restrict__ WE,
    short* __restrict__ WtA, short* __restrict__ WtB, short* __restrict__ WtC,
    short* __restrict__ WtD, short* __restrict__ WtE,
    int* __restrict__ deg, int n) {
  int t = threadIdx.x;
  if (blockIdx.x < 5) {
    const float* Ws[5] = {WA, WB, WC, WD, WE};
    short* Os[5] = {WtA, WtB, WtC, WtD, WtE};
    const float* W = Ws[blockIdx.x];
    short* O = Os[blockIdx.x];
    int c = t & 127, h = t >> 7;
    for (int p = 0; p < 8; ++p) {
      int k0 = (h * 8 + p) * 8;
      bf16x8 v;
      #pragma unroll
      for (int j = 0; j < 8; ++j) v[j] = f2bf(W[(size_t)(k0 + j) * DD + c]);
      *(bf16x8*)&O[(size_t)c * DD + k0] = v;
    }
  } else {
    int i = (blockIdx.x - 5) * 256 + t;
    if (i < n) deg[i] = 0;
  }
}

// ---------------- CSR build ----------------
__global__ __launch_bounds__(256) void k_hist(const int* __restrict__ dst, int* __restrict__ deg, int E) {
  int e = blockIdx.x * 256 + threadIdx.x;
  if (e < E) atomicAdd(&deg[dst[e]], 1);
}

__global__ __launch_bounds__(256) void k_scan1(const int* __restrict__ deg, int* __restrict__ off,
                                               int* __restrict__ totals, int n) {
  __shared__ int sm[256];
  int t = threadIdx.x;
  int i = blockIdx.x * 256 + t;
  int v = (i < n) ? deg[i] : 0;
  sm[t] = v;
  __syncthreads();
  int acc = v;
  #pragma unroll
  for (int d = 1; d < 256; d <<= 1) {
    int add = (t >= d) ? sm[t - d] : 0;
    __syncthreads();
    acc += add;
    sm[t] = acc;
    __syncthreads();
  }
  if (i < n) off[i] = acc - v;          // exclusive
  if (t == 255) totals[blockIdx.x] = acc;
}

__global__ __launch_bounds__(256) void k_scan2(const int* __restrict__ totals, int* __restrict__ boff, int nb) {
  __shared__ int sm[256];
  int t = threadIdx.x;
  int v = (t < nb) ? totals[t] : 0;
  sm[t] = v;
  __syncthreads();
  int acc = v;
  #pragma unroll
  for (int d = 1; d < 256; d <<= 1) {
    int add = (t >= d) ? sm[t - d] : 0;
    __syncthreads();
    acc += add;
    sm[t] = acc;
    __syncthreads();
  }
  boff[t] = acc - v;
}

__global__ __launch_bounds__(256) void k_scan3(int* __restrict__ off, const int* __restrict__ boff,
                                               int* __restrict__ cursor, int n) {
  int i = blockIdx.x * 256 + threadIdx.x;
  if (i < n) {
    int o = off[i] + boff[blockIdx.x];
    off[i] = o;
    cursor[i] = o;
  }
}

__global__ __launch_bounds__(256) void k_fill(const int* __restrict__ dst, const int* __restrict__ src,
                                              int* __restrict__ cursor, int* __restrict__ list,
                                              int* __restrict__ srcS, int* __restrict__ posOf, int E) {
  int e = blockIdx.x * 256 + threadIdx.x;
  if (e < E) {
    int p = atomicAdd(&cursor[dst[e]], 1);
    list[p] = e;
    srcS[p] = src[e];
    posOf[e] = p;
  }
}

// ---------------- node-side GEMMs (swapped MFMA; register-local epilogue) ----------
__global__ __launch_bounds__(256) void k_nodegemm(
    const float* __restrict__ x,
    const short* __restrict__ WtA, const float* __restrict__ bA,
    const short* __restrict__ WtB, const float* __restrict__ bB,
    const short* __restrict__ WtD, const float* __restrict__ bD,
    const short* __restrict__ WtE, const float* __restrict__ bE,
    short* __restrict__ Axh, short* __restrict__ Bxh,
    short* __restrict__ Dxh, short* __restrict__ Exh, int n) {
  int t = threadIdx.x;
  int w = t >> 6, l = t & 63, lg = l >> 4, lc = l & 15;
  int m0 = blockIdx.x * 64;
  int row = m0 + w * 16 + lc;
  bool valid = row < n;
  int rowc = valid ? row : n - 1;

  const float* xr = x + (size_t)rowc * DD;
  bf16x8 af[4];
  #pragma unroll
  for (int kk = 0; kk < 4; ++kk) {
    float4 a0 = *(const float4*)&xr[kk * 32 + lg * 8];
    float4 a1 = *(const float4*)&xr[kk * 32 + lg * 8 + 4];
    af[kk][0] = f2bf(a0.x); af[kk][1] = f2bf(a0.y); af[kk][2] = f2bf(a0.z); af[kk][3] = f2bf(a0.w);
    af[kk][4] = f2bf(a1.x); af[kk][5] = f2bf(a1.y); af[kk][6] = f2bf(a1.z); af[kk][7] = f2bf(a1.w);
  }

  const short* Wt[4] = {WtA, WtB, WtD, WtE};
  const float* bs[4] = {bA, bB, bD, bE};
  short* Os[4] = {Axh, Bxh, Dxh, Exh};

  #pragma unroll
  for (int mi = 0; mi < 4; ++mi) {
    const short* Wm = Wt[mi];
    f32x4 acc[8] = {};
    #pragma unroll
    for (int kk = 0; kk < 4; ++kk) {
      #pragma unroll
      for (int tt = 0; tt < 8; ++tt) {
        bf16x8 bfv = *(const bf16x8*)&Wm[(size_t)(tt * 16 + lc) * DD + kk * 32 + lg * 8];
        acc[tt] = __builtin_amdgcn_mfma_f32_16x16x32_bf16(bfv, af[kk], acc[tt], 0, 0, 0);
      }
    }
    if (valid) {
      short* O = Os[mi];
      #pragma unroll
      for (int tt = 0; tt < 8; ++tt) {
        int f0 = tt * 16 + lg * 4;
        float4 bc = *(const float4*)&bs[mi][f0];
        short4 o;
        o.x = f2bf(acc[tt][0] + bc.x);
        o.y = f2bf(acc[tt][1] + bc.y);
        o.z = f2bf(acc[tt][2] + bc.z);
        o.w = f2bf(acc[tt][3] + bc.w);
        *(short4*)&O[(size_t)row * DD + f0] = o;
      }
    }
  }
}

// ---------------- edge kernel: 512-thread blocks (8 waves share 32KB WtC LDS) ----------------
// LDS 66.8KB -> 2 blocks/CU = 16 waves/CU (was 12 at 256-thr). Tile = 128 edges.
// Per-wave code identical to R13; dv/sv issued at loop top, consumed same iteration.
__global__ __launch_bounds__(512) void k_edge(
    const float* __restrict__ e, const short* __restrict__ WtC, const float* __restrict__ bC,
    const int* __restrict__ srcI, const int* __restrict__ dstI, const int* __restrict__ posOf,
    const short* __restrict__ Dxh, const short* __restrict__ Exh,
    short* __restrict__ eijS, float* __restrict__ pE, int Etot, int ntiles) {
  __shared__ __align__(16) short lds_wt[32 * 64 * 8];       // 32 KB fragment-major WtC (shared by 8 waves)
  __shared__ __align__(16) short es[8][16][136];            // per-wave restage (34.8 KB)
  int t = threadIdx.x;
  int w = t >> 6, l = t & 63, lg = l >> 4, lc = l & 15;

  #pragma unroll
  for (int i = 0; i < 4; ++i) {
    int slot = w * 4 + i;
    int tt = slot >> 2, kk = slot & 3;
    bf16x8 v = *(const bf16x8*)&WtC[(size_t)(tt * 16 + lc) * DD + kk * 32 + lg * 8];
    *(bf16x8*)&lds_wt[(slot * 64 + l) * 8] = v;
  }
  __syncthreads();

  float bCv[8];
  #pragma unroll
  for (int tt = 0; tt < 8; ++tt) bCv[tt] = bC[tt * 16 + lc];

  float se[8] = {}, qe[8] = {};

  const int stride = gridDim.x;
  int tile = blockIdx.x;

  float4 e32[8];
  int dnN[4], snN[4], posN[4];

  {
    size_t m0 = (size_t)tile * 128;
    size_t row = m0 + w * 16 + lc;
    if (row >= (size_t)Etot) row = Etot - 1;
    const float* er = e + row * DD;
    #pragma unroll
    for (int kk = 0; kk < 4; ++kk) {
      e32[kk * 2]     = *(const float4*)&er[kk * 32 + lg * 8];
      e32[kk * 2 + 1] = *(const float4*)&er[kk * 32 + lg * 8 + 4];
    }
    #pragma unroll
    for (int z = 0; z < 4; ++z) {
      size_t erow = m0 + w * 16 + z * 4 + lg;
      if (erow >= (size_t)Etot) erow = Etot - 1;
      dnN[z] = dstI[erow]; snN[z] = srcI[erow]; posN[z] = posOf[erow];
    }
  }

  for (; tile < ntiles; tile += stride) {
    int dn[4], sn[4], pos[4];
    #pragma unroll
    for (int z = 0; z < 4; ++z) { dn[z] = dnN[z]; sn[z] = snN[z]; pos[z] = posN[z]; }

    bf16x8 dv[4], sv[4];
    #pragma unroll
    for (int z = 0; z < 4; ++z) {
      dv[z] = *(const bf16x8*)&Dxh[(size_t)dn[z] * DD + lc * 8];
      sv[z] = *(const bf16x8*)&Exh[(size_t)sn[z] * DD + lc * 8];
    }

    bf16x8 af[4];
    #pragma unroll
    for (int kk = 0; kk < 4; ++kk) {
      float4 a0 = e32[kk * 2], a1 = e32[kk * 2 + 1];
      af[kk][0] = f2bf(a0.x); af[kk][1] = f2bf(a0.y); af[kk][2] = f2bf(a0.z); af[kk][3] = f2bf(a0.w);
      af[kk][4] = f2bf(a1.x); af[kk][5] = f2bf(a1.y); af[kk][6] = f2bf(a1.z); af[kk][7] = f2bf(a1.w);
    }

    int nt = tile + stride;
    if (nt < ntiles) {
      size_t m0n = (size_t)nt * 128;
      size_t row = m0n + w * 16 + lc;
      if (row >= (size_t)Etot) row = Etot - 1;
      const float* er = e + row * DD;
      #pragma unroll
      for (int kk = 0; kk < 4; ++kk) {
        e32[kk * 2]     = *(const float4*)&er[kk * 32 + lg * 8];
        e32[kk * 2 + 1] = *(const float4*)&er[kk * 32 + lg * 8 + 4];
      }
      #pragma unroll
      for (int z = 0; z < 4; ++z) {
        size_t erow = m0n + w * 16 + z * 4 + lg;
        if (erow >= (size_t)Etot) erow = Etot - 1;
        dnN[z] = dstI[erow]; snN[z] = srcI[erow]; posN[z] = posOf[erow];
      }
    }

    f32x4 acc[8] = {};
    #pragma unroll
    for (int kk = 0; kk < 4; ++kk) {
      #pragma unroll
      for (int tt = 0; tt < 8; ++tt) {
        bf16x8 bfv = *(const bf16x8*)&lds_wt[((tt * 4 + kk) * 64 + l) * 8];
        acc[tt] = __builtin_amdgcn_mfma_f32_16x16x32_bf16(af[kk], bfv, acc[tt], 0, 0, 0);
      }
    }

    #pragma unroll
    for (int tt = 0; tt < 8; ++tt) {
      int col = tt * 16 + lc;
      #pragma unroll
      for (int j = 0; j < 4; ++j)
        es[w][lg * 4 + j][col] = f2bf(acc[tt][j] + bCv[tt]);
    }
    asm volatile("s_waitcnt lgkmcnt(0)" ::: "memory");
    __builtin_amdgcn_sched_barrier(0);

    size_t m0 = (size_t)tile * 128;
    #pragma unroll
    for (int z = 0; z < 4; ++z) {
      size_t erow = m0 + w * 16 + z * 4 + lg;
      if (erow < (size_t)Etot) {
        int r = z * 4 + lg;
        bf16x8 cv = *(const bf16x8*)&es[w][r][lc * 8];
        bf16x8 o;
        #pragma unroll
        for (int j = 0; j < 8; ++j) {
          float v = bf2f(cv[j]) + bf2f(dv[z][j]) + bf2f(sv[z][j]);
          se[j] += v; qe[j] += v * v;
          o[j] = f2bf(v);
        }
        *(bf16x8*)&eijS[(size_t)pos[z] * DD + lc * 8] = o;
      }
    }
    __builtin_amdgcn_sched_barrier(0);
  }

  // per-wave stat partials (pE layout [GE*8][256])
  #pragma unroll
  for (int j = 0; j < 8; ++j) {
    se[j] += __shfl_xor(se[j], 16); se[j] += __shfl_xor(se[j], 32);
    qe[j] += __shfl_xor(qe[j], 16); qe[j] += __shfl_xor(qe[j], 32);
  }
  if (lg == 0) {
    size_t base = ((size_t)blockIdx.x * 8 + w) * 256;
    #pragma unroll
    for (int j = 0; j < 8; ++j) {
      pE[base + lc * 8 + j] = se[j];
      pE[base + 128 + lc * 8 + j] = qe[j];
    }
  }
}

// ---------------- gather helper ----------------
__device__ __forceinline__ void proc_edge(int id, bf16x8 ev, bf16x8 bv,
                                          const float* su, const float* hu,
                                          float* num, float* den,
                                          float* __restrict__ oute, int fi) {
  float va[8];
  #pragma unroll
  for (int j = 0; j < 8; ++j) {
    float v0 = bf2f(ev[j]);
    va[j] = fmaxf(0.f, v0 * su[j] + hu[j]);
    float g0 = 1.f / (1.f + __expf(-v0));
    num[j] += g0 * bf2f(bv[j]);
    den[j] += g0;
  }
  float4 oa, ob;
  oa.x = va[0]; oa.y = va[1]; oa.z = va[2]; oa.w = va[3];
  ob.x = va[4]; ob.y = va[5]; ob.z = va[6]; ob.w = va[7];
  *(float4*)&oute[(size_t)id * DD + fi * 8] = oa;
  *(float4*)&oute[(size_t)id * DD + fi * 8 + 4] = ob;
}

// ---------------- gather: 16/8/4-chain loops, node-level prefetch, bf16 x_pre --------------
__global__ __launch_bounds__(256) void k_gather(
    const int* __restrict__ off, const int* __restrict__ deg, const int* __restrict__ list,
    const int* __restrict__ srcS, const short* __restrict__ eijS, const short* __restrict__ Bxh,
    const short* __restrict__ Axh, const float* __restrict__ stE,
    short* __restrict__ outxh, float* __restrict__ oute,
    float* __restrict__ pX, int n) {
  int t = threadIdx.x;
  int w = t >> 6, l = t & 63;
  int qw = l >> 4, fi = l & 15;
  int waveId = blockIdx.x * 4 + w;
  const int nwaves = NB_G * 4;

  float su[8], hu[8];
  {
    float4 s0 = *(const float4*)&stE[fi * 8], s1 = *(const float4*)&stE[fi * 8 + 4];
    float4 h0 = *(const float4*)&stE[128 + fi * 8], h1 = *(const float4*)&stE[128 + fi * 8 + 4];
    su[0] = s0.x; su[1] = s0.y; su[2] = s0.z; su[3] = s0.w;
    su[4] = s1.x; su[5] = s1.y; su[6] = s1.z; su[7] = s1.w;
    hu[0] = h0.x; hu[1] = h0.y; hu[2] = h0.z; hu[3] = h0.w;
    hu[4] = h1.x; hu[5] = h1.y; hu[6] = h1.z; hu[7] = h1.w;
  }

  float sx[4] = {}, qx[4] = {};
  int c0 = fi * 8 + ((qw & 1) * 4);

  int startC = 0, dgC = 0;
  if (waveId < n) { startC = off[waveId]; dgC = deg[waveId]; }

  for (int node = waveId; node < n; node += nwaves) {
    int start = startC, dg = dgC;
    int nn = node + nwaves;
    if (nn < n) { startC = off[nn]; dgC = deg[nn]; }
    short4 ax = *(const short4*)&Axh[(size_t)node * DD + (qw < 2 ? c0 : fi * 8)];

    float num[8] = {}, den[8] = {};
    int k = qw;
    for (; k + 12 < dg; k += 16) {   // 4 chains/lane
      int p0 = start + k, p1 = p0 + 4, p2 = p0 + 8, p3 = p0 + 12;
      int id0 = list[p0], id1 = list[p1], id2 = list[p2], id3 = list[p3];
      int s0 = srcS[p0], s1 = srcS[p1], s2 = srcS[p2], s3 = srcS[p3];
      bf16x8 e0 = *(const bf16x8*)&eijS[(size_t)p0 * DD + fi * 8];
      bf16x8 e1 = *(const bf16x8*)&eijS[(size_t)p1 * DD + fi * 8];
      bf16x8 e2 = *(const bf16x8*)&eijS[(size_t)p2 * DD + fi * 8];
      bf16x8 e3 = *(const bf16x8*)&eijS[(size_t)p3 * DD + fi * 8];
      bf16x8 b0 = *(const bf16x8*)&Bxh[(size_t)s0 * DD + fi * 8];
      bf16x8 b1 = *(const bf16x8*)&Bxh[(size_t)s1 * DD + fi * 8];
      bf16x8 b2 = *(const bf16x8*)&Bxh[(size_t)s2 * DD + fi * 8];
      bf16x8 b3 = *(const bf16x8*)&Bxh[(size_t)s3 * DD + fi * 8];
      proc_edge(id0, e0, b0, su, hu, num, den, oute, fi);
      proc_edge(id1, e1, b1, su, hu, num, den, oute, fi);
      proc_edge(id2, e2, b2, su, hu, num, den, oute, fi);
      proc_edge(id3, e3, b3, su, hu, num, den, oute, fi);
    }
    for (; k + 4 < dg; k += 8) {     // 2 chains/lane
      int p0 = start + k, p1 = p0 + 4;
      int id0 = list[p0], id1 = list[p1];
      int s0 = srcS[p0], s1 = srcS[p1];
      bf16x8 e0 = *(const bf16x8*)&eijS[(size_t)p0 * DD + fi * 8];
      bf16x8 e1 = *(const bf16x8*)&eijS[(size_t)p1 * DD + fi * 8];
      bf16x8 b0 = *(const bf16x8*)&Bxh[(size_t)s0 * DD + fi * 8];
      bf16x8 b1 = *(const bf16x8*)&Bxh[(size_t)s1 * DD + fi * 8];
      proc_edge(id0, e0, b0, su, hu, num, den, oute, fi);
      proc_edge(id1, e1, b1, su, hu, num, den, oute, fi);
    }
    for (; k < dg; k += 4) {         // 1 chain
      int p0 = start + k;
      int id0 = list[p0];
      int s0 = srcS[p0];
      bf16x8 e0 = *(const bf16x8*)&eijS[(size_t)p0 * DD + fi * 8];
      bf16x8 b0 = *(const bf16x8*)&Bxh[(size_t)s0 * DD + fi * 8];
      proc_edge(id0, e0, b0, su, hu, num, den, oute, fi);
    }
    #pragma unroll
    for (int j = 0; j < 8; ++j) {
      num[j] += __shfl_xor(num[j], 16); num[j] += __shfl_xor(num[j], 32);
      den[j] += __shfl_xor(den[j], 16); den[j] += __shfl_xor(den[j], 32);
    }
    if (qw < 2) {
      short axa[4] = {ax.x, ax.y, ax.z, ax.w};
      short4 o;
      short ov[4];
      #pragma unroll
      for (int j = 0; j < 4; ++j) {
        int jj = qw * 4 + j;
        float aggr = num[jj] / (den[jj] + 1e-6f);
        float xp = bf2f(axa[j]) + aggr;
        ov[j] = f2bf(xp);
        sx[j] += xp; qx[j] += xp * xp;
      }
      o.x = ov[0]; o.y = ov[1]; o.z = ov[2]; o.w = ov[3];
      *(short4*)&outxh[(size_t)node * DD + c0] = o;
    }
  }

  __shared__ float lsX[4][128], lqX[4][128];
  if (qw < 2) {
    #pragma unroll
    for (int j = 0; j < 4; ++j) { lsX[w][fi * 8 + qw * 4 + j] = sx[j]; lqX[w][fi * 8 + qw * 4 + j] = qx[j]; }
  }
  __syncthreads();
  if (t < 128) {
    float a = lsX[0][t] + lsX[1][t] + lsX[2][t] + lsX[3][t];
    float b = lqX[0][t] + lqX[1][t] + lqX[2][t] + lqX[3][t];
    pX[(size_t)blockIdx.x * 256 + t] = a;
    pX[(size_t)blockIdx.x * 256 + 128 + t] = b;
  }
}

// reduce partials -> folded BN affine: stats[c]=scale, stats[128+c]=shift
__global__ __launch_bounds__(256) void k_reduce(const float* __restrict__ part, int nblk, float invcnt,
                                                const float* __restrict__ gamma, const float* __restrict__ beta,
                                                float* __restrict__ stats) {
  int c = blockIdx.x, t = threadIdx.x;
  float a = 0.f, b = 0.f;
  for (int k = t; k < nblk; k += 256) {
    a += part[(size_t)k * 256 + c];
    b += part[(size_t)k * 256 + 128 + c];
  }
  #pragma unroll
  for (int o = 32; o > 0; o >>= 1) { a += __shfl_down(a, o); b += __shfl_down(b, o); }
  __shared__ float ra[4], rb[4];
  int l = t & 63, w = t >> 6;
  if (l == 0) { ra[w] = a; rb[w] = b; }
  __syncthreads();
  if (t == 0) {
    a = ra[0] + ra[1] + ra[2] + ra[3];
    b = rb[0] + rb[1] + rb[2] + rb[3];
    float mean = a * invcnt;
    float var = b * invcnt - mean * mean;   // biased variance
    float istd = rsqrtf(var + 1e-5f);
    float scale = gamma[c] * istd;
    stats[c] = scale;
    stats[128 + c] = beta[c] - mean * scale;
  }
}

// ---------------- finalize x: bf16 x_pre -> BN+ReLU -> f32 out ----------------
__global__ __launch_bounds__(256) void k_xfinal(const short* __restrict__ vh, const float* __restrict__ st,
                                                float* __restrict__ out, size_t n8) {
  size_t i = (size_t)blockIdx.x * 256 + threadIdx.x;
  if (i >= n8) return;
  bf16x8 u = *(const bf16x8*)&vh[i * 8];
  int f0 = (int)((i * 8) & 127);
  float4 s0 = *(const float4*)&st[f0], s1 = *(const float4*)&st[f0 + 4];
  float4 h0 = *(const float4*)&st[128 + f0], h1 = *(const float4*)&st[128 + f0 + 4];
  float4 a, b;
  a.x = fmaxf(0.f, bf2f(u[0]) * s0.x + h0.x);
  a.y = fmaxf(0.f, bf2f(u[1]) * s0.y + h0.y);
  a.z = fmaxf(0.f, bf2f(u[2]) * s0.z + h0.z);
  a.w = fmaxf(0.f, bf2f(u[3]) * s0.w + h0.w);
  b.x = fmaxf(0.f, bf2f(u[4]) * s1.x + h1.x);
  b.y = fmaxf(0.f, bf2f(u[5]) * s1.y + h1.y);
  b.z = fmaxf(0.f, bf2f(u[6]) * s1.z + h1.z);
  b.w = fmaxf(0.f, bf2f(u[7]) * s1.w + h1.w);
  *(float4*)&out[i * 8] = a;
  *(float4*)&out[i * 8 + 4] = b;
}

extern "C" void kernel_launch(void* const* d_in, const int* in_sizes, int n_in,
                              void* d_out, int out_size, void* d_ws, size_t ws_size,
                              hipStream_t stream) {
  const float* x  = (const float*)d_in[0];
  const float* e  = (const float*)d_in[1];
  const int*   ei = (const int*)d_in[2];
  const float* WA = (const float*)d_in[3];  const float* bA = (const float*)d_in[4];
  const float* WB = (const float*)d_in[5];  const float* bB = (const float*)d_in[6];
  const float* WC = (const float*)d_in[7];  const float* bC = (const float*)d_in[8];
  const float* WD = (const float*)d_in[9];  const float* bD = (const float*)d_in[10];
  const float* WE = (const float*)d_in[11]; const float* bE = (const float*)d_in[12];
  const float* gx = (const float*)d_in[13]; const float* bx = (const float*)d_in[14];
  const float* ge = (const float*)d_in[15]; const float* be = (const float*)d_in[16];

  int N = in_sizes[0] / DD;
  int E = in_sizes[2] / 2;
  const int* srcI = ei;       // edge_index[0]
  const int* dstI = ei + E;   // edge_index[1]

  float* outx = (float*)d_out;
  float* oute = (float*)d_out + (size_t)N * DD;

  int ntilesE = (E + 127) / 128;

  char* wp = (char*)d_ws;
  auto alloc = [&](size_t sz) { char* p = wp; wp += (sz + 255) & ~(size_t)255; return p; };
  short* Axh    = (short*)alloc((size_t)N * DD * 2);
  short* Bxh    = (short*)alloc((size_t)N * DD * 2);
  short* Dxh    = (short*)alloc((size_t)N * DD * 2);
  short* Exh    = (short*)alloc((size_t)N * DD * 2);
  short* eijS   = (short*)alloc((size_t)E * DD * 2);
  short* outxh  = (short*)alloc((size_t)N * DD * 2);
  int*   deg    = (int*)alloc((size_t)N * 4);
  int*   off    = (int*)alloc((size_t)N * 4);
  int*   cursor = (int*)alloc((size_t)N * 4);
  int*   totals = (int*)alloc(1024);
  int*   boff   = (int*)alloc(1024);
  int*   list   = (int*)alloc((size_t)E * 4);
  int*   srcS   = (int*)alloc((size_t)E * 4);
  int*   posOf  = (int*)alloc((size_t)E * 4);
  float* pE     = (float*)alloc((size_t)GE * 8 * 256 * 4);   // per-wave partials
  float* pX     = (float*)alloc((size_t)NB_G * 256 * 4);
  float* statsE = (float*)alloc(1024);
  float* statsX = (float*)alloc(1024);
  short* WtA    = (short*)alloc((size_t)DD * DD * 2);
  short* WtB    = (short*)alloc((size_t)DD * DD * 2);
  short* WtC    = (short*)alloc((size_t)DD * DD * 2);
  short* WtD    = (short*)alloc((size_t)DD * DD * 2);
  short* WtE    = (short*)alloc((size_t)DD * DD * 2);
  (void)ws_size; (void)n_in; (void)out_size;

  int nsb = (N + 255) / 256;

  k_prep<<<5 + nsb, 256, 0, stream>>>(WA, WB, WC, WD, WE, WtA, WtB, WtC, WtD, WtE, deg, N);
  k_hist<<<(E + 255) / 256, 256, 0, stream>>>(dstI, deg, E);
  k_scan1<<<nsb, 256, 0, stream>>>(deg, off, totals, N);
  k_scan2<<<1, 256, 0, stream>>>(totals, boff, nsb);
  k_scan3<<<nsb, 256, 0, stream>>>(off, boff, cursor, N);
  k_fill<<<(E + 255) / 256, 256, 0, stream>>>(dstI, srcI, cursor, list, srcS, posOf, E);

  k_nodegemm<<<(N + 63) / 64, 256, 0, stream>>>(x, WtA, bA, WtB, bB, WtD, bD, WtE, bE,
                                                Axh, Bxh, Dxh, Exh, N);
  k_edge<<<GE, 512, 0, stream>>>(e, WtC, bC, srcI, dstI, posOf, Dxh, Exh, eijS, pE, E, ntilesE);
  k_reduce<<<128, 256, 0, stream>>>(pE, GE * 8, 1.0f / (float)E, ge, be, statsE);

  k_gather<<<NB_G, 256, 0, stream>>>(off, deg, list, srcS, eijS, Bxh, Axh, statsE,
                                     outxh, oute, pX, N);
  k_reduce<<<128, 256, 0, stream>>>(pX, NB_G, 1.0f / (float)N, gx, bx, statsX);
  k_xfinal<<<(int)(((size_t)N * DD / 8 + 255) / 256), 256, 0, stream>>>(outxh, statsX, outx, (size_t)N * DD / 8);
}

// Round 15
// 566.978 us; speedup vs baseline: 1.0084x; 1.0084x over previous
//
#include <hip/hip_runtime.h>
#include <stdint.h>

#define DD 128
#define NB_G 2048   // k_gather blocks
#define GE   2048   // k_edge persistent blocks

using f32x4  = __attribute__((ext_vector_type(4))) float;
using bf16x8 = __attribute__((ext_vector_type(8))) short;

__device__ __forceinline__ float bf2f(short u) {
  union { unsigned int i; float f; } c;
  c.i = ((unsigned int)(unsigned short)u) << 16;
  return c.f;
}
__device__ __forceinline__ short f2bf(float f) {
  union { float f; unsigned int i; } c;
  c.f = f;
  unsigned int u = c.i;
  u += 0x7fffu + ((u >> 16) & 1u);
  return (short)(u >> 16);
}

// ---------------- prep: weight convert+transpose (blocks 0-4) + zero deg (blocks 5+) --------
__global__ __launch_bounds__(256) void k_prep(
    const float* __restrict__ WA, const float* __restrict__ WB, const float* __restrict__ WC,
    const float* __restrict__ WD, const float* __restrict__ WE,
    short* __restrict__ WtA, short* __restrict__ WtB, short* __restrict__ WtC,
    short* __restrict__ WtD, short* __restrict__ WtE,
    int* __restrict__ deg, int n) {
  int t = threadIdx.x;
  if (blockIdx.x < 5) {
    const float* Ws[5] = {WA, WB, WC, WD, WE};
    short* Os[5] = {WtA, WtB, WtC, WtD, WtE};
    const float* W = Ws[blockIdx.x];
    short* O = Os[blockIdx.x];
    int c = t & 127, h = t >> 7;
    for (int p = 0; p < 8; ++p) {
      int k0 = (h * 8 + p) * 8;
      bf16x8 v;
      #pragma unroll
      for (int j = 0; j < 8; ++j) v[j] = f2bf(W[(size_t)(k0 + j) * DD + c]);
      *(bf16x8*)&O[(size_t)c * DD + k0] = v;
    }
  } else {
    int i = (blockIdx.x - 5) * 256 + t;
    if (i < n) deg[i] = 0;
  }
}

// ---------------- CSR build ----------------
__global__ __launch_bounds__(256) void k_hist(const int* __restrict__ dst, int* __restrict__ deg, int E) {
  int e = blockIdx.x * 256 + threadIdx.x;
  if (e < E) atomicAdd(&deg[dst[e]], 1);
}

__global__ __launch_bounds__(256) void k_scan1(const int* __restrict__ deg, int* __restrict__ off,
                                               int* __restrict__ totals, int n) {
  __shared__ int sm[256];
  int t = threadIdx.x;
  int i = blockIdx.x * 256 + t;
  int v = (i < n) ? deg[i] : 0;
  sm[t] = v;
  __syncthreads();
  int acc = v;
  #pragma unroll
  for (int d = 1; d < 256; d <<= 1) {
    int add = (t >= d) ? sm[t - d] : 0;
    __syncthreads();
    acc += add;
    sm[t] = acc;
    __syncthreads();
  }
  if (i < n) off[i] = acc - v;          // exclusive
  if (t == 255) totals[blockIdx.x] = acc;
}

__global__ __launch_bounds__(256) void k_scan2(const int* __restrict__ totals, int* __restrict__ boff, int nb) {
  __shared__ int sm[256];
  int t = threadIdx.x;
  int v = (t < nb) ? totals[t] : 0;
  sm[t] = v;
  __syncthreads();
  int acc = v;
  #pragma unroll
  for (int d = 1; d < 256; d <<= 1) {
    int add = (t >= d) ? sm[t - d] : 0;
    __syncthreads();
    acc += add;
    sm[t] = acc;
    __syncthreads();
  }
  boff[t] = acc - v;
}

__global__ __launch_bounds__(256) void k_scan3(int* __restrict__ off, const int* __restrict__ boff,
                                               int* __restrict__ cursor, int n) {
  int i = blockIdx.x * 256 + threadIdx.x;
  if (i < n) {
    int o = off[i] + boff[blockIdx.x];
    off[i] = o;
    cursor[i] = o;
  }
}

__global__ __launch_bounds__(256) void k_fill(const int* __restrict__ dst, const int* __restrict__ src,
                                              int* __restrict__ cursor, int* __restrict__ list,
                                              int* __restrict__ srcS, int* __restrict__ posOf, int E) {
  int e = blockIdx.x * 256 + threadIdx.x;
  if (e < E) {
    int p = atomicAdd(&cursor[dst[e]], 1);
    list[p] = e;
    srcS[p] = src[e];
    posOf[e] = p;
  }
}

// ---------------- node-side GEMMs (swapped MFMA; register-local epilogue) ----------
__global__ __launch_bounds__(256) void k_nodegemm(
    const float* __restrict__ x,
    const short* __restrict__ WtA, const float* __restrict__ bA,
    const short* __restrict__ WtB, const float* __restrict__ bB,
    const short* __restrict__ WtD, const float* __restrict__ bD,
    const short* __restrict__ WtE, const float* __restrict__ bE,
    short* __restrict__ Axh, short* __restrict__ Bxh,
    short* __restrict__ Dxh, short* __restrict__ Exh, int n) {
  int t = threadIdx.x;
  int w = t >> 6, l = t & 63, lg = l >> 4, lc = l & 15;
  int m0 = blockIdx.x * 64;
  int row = m0 + w * 16 + lc;
  bool valid = row < n;
  int rowc = valid ? row : n - 1;

  const float* xr = x + (size_t)rowc * DD;
  bf16x8 af[4];
  #pragma unroll
  for (int kk = 0; kk < 4; ++kk) {
    float4 a0 = *(const float4*)&xr[kk * 32 + lg * 8];
    float4 a1 = *(const float4*)&xr[kk * 32 + lg * 8 + 4];
    af[kk][0] = f2bf(a0.x); af[kk][1] = f2bf(a0.y); af[kk][2] = f2bf(a0.z); af[kk][3] = f2bf(a0.w);
    af[kk][4] = f2bf(a1.x); af[kk][5] = f2bf(a1.y); af[kk][6] = f2bf(a1.z); af[kk][7] = f2bf(a1.w);
  }

  const short* Wt[4] = {WtA, WtB, WtD, WtE};
  const float* bs[4] = {bA, bB, bD, bE};
  short* Os[4] = {Axh, Bxh, Dxh, Exh};

  #pragma unroll
  for (int mi = 0; mi < 4; ++mi) {
    const short* Wm = Wt[mi];
    f32x4 acc[8] = {};
    #pragma unroll
    for (int kk = 0; kk < 4; ++kk) {
      #pragma unroll
      for (int tt = 0; tt < 8; ++tt) {
        bf16x8 bfv = *(const bf16x8*)&Wm[(size_t)(tt * 16 + lc) * DD + kk * 32 + lg * 8];
        acc[tt] = __builtin_amdgcn_mfma_f32_16x16x32_bf16(bfv, af[kk], acc[tt], 0, 0, 0);
      }
    }
    if (valid) {
      short* O = Os[mi];
      #pragma unroll
      for (int tt = 0; tt < 8; ++tt) {
        int f0 = tt * 16 + lg * 4;
        float4 bc = *(const float4*)&bs[mi][f0];
        short4 o;
        o.x = f2bf(acc[tt][0] + bc.x);
        o.y = f2bf(acc[tt][1] + bc.y);
        o.z = f2bf(acc[tt][2] + bc.z);
        o.w = f2bf(acc[tt][3] + bc.w);
        *(short4*)&O[(size_t)row * DD + f0] = o;
      }
    }
  }
}

// ---------------- edge kernel: pipelined grid-stride; WtC staged once in LDS ----------------
__global__ __launch_bounds__(256) void k_edge(
    const float* __restrict__ e, const short* __restrict__ WtC, const float* __restrict__ bC,
    const int* __restrict__ srcI, const int* __restrict__ dstI, const int* __restrict__ posOf,
    const short* __restrict__ Dxh, const short* __restrict__ Exh,
    short* __restrict__ eijS, float* __restrict__ pE, int Etot, int ntiles) {
  __shared__ __align__(16) short lds_wt[32 * 64 * 8];       // 32 KB fragment-major WtC
  __shared__ __align__(16) short es[4][16][136];            // per-wave restage
  int t = threadIdx.x;
  int w = t >> 6, l = t & 63, lg = l >> 4, lc = l & 15;

  #pragma unroll
  for (int i = 0; i < 8; ++i) {
    int slot = w * 8 + i;
    int tt = slot >> 2, kk = slot & 3;
    bf16x8 v = *(const bf16x8*)&WtC[(size_t)(tt * 16 + lc) * DD + kk * 32 + lg * 8];
    *(bf16x8*)&lds_wt[(slot * 64 + l) * 8] = v;
  }
  __syncthreads();

  float bCv[8];
  #pragma unroll
  for (int tt = 0; tt < 8; ++tt) bCv[tt] = bC[tt * 16 + lc];

  float se[8] = {}, qe[8] = {};

  const int stride = gridDim.x;
  int tile = blockIdx.x;

  float4 e32[8];
  int dnN[4], snN[4], posN[4];

  {
    size_t m0 = (size_t)tile * 64;
    size_t row = m0 + w * 16 + lc;
    if (row >= (size_t)Etot) row = Etot - 1;
    const float* er = e + row * DD;
    #pragma unroll
    for (int kk = 0; kk < 4; ++kk) {
      e32[kk * 2]     = *(const float4*)&er[kk * 32 + lg * 8];
      e32[kk * 2 + 1] = *(const float4*)&er[kk * 32 + lg * 8 + 4];
    }
    #pragma unroll
    for (int z = 0; z < 4; ++z) {
      size_t erow = m0 + w * 16 + z * 4 + lg;
      if (erow >= (size_t)Etot) erow = Etot - 1;
      dnN[z] = dstI[erow]; snN[z] = srcI[erow]; posN[z] = posOf[erow];
    }
  }

  for (; tile < ntiles; tile += stride) {
    int dn[4], sn[4], pos[4];
    #pragma unroll
    for (int z = 0; z < 4; ++z) { dn[z] = dnN[z]; sn[z] = snN[z]; pos[z] = posN[z]; }

    bf16x8 dv[4], sv[4];
    #pragma unroll
    for (int z = 0; z < 4; ++z) {
      dv[z] = *(const bf16x8*)&Dxh[(size_t)dn[z] * DD + lc * 8];
      sv[z] = *(const bf16x8*)&Exh[(size_t)sn[z] * DD + lc * 8];
    }

    bf16x8 af[4];
    #pragma unroll
    for (int kk = 0; kk < 4; ++kk) {
      float4 a0 = e32[kk * 2], a1 = e32[kk * 2 + 1];
      af[kk][0] = f2bf(a0.x); af[kk][1] = f2bf(a0.y); af[kk][2] = f2bf(a0.z); af[kk][3] = f2bf(a0.w);
      af[kk][4] = f2bf(a1.x); af[kk][5] = f2bf(a1.y); af[kk][6] = f2bf(a1.z); af[kk][7] = f2bf(a1.w);
    }

    int nt = tile + stride;
    if (nt < ntiles) {
      size_t m0n = (size_t)nt * 64;
      size_t row = m0n + w * 16 + lc;
      if (row >= (size_t)Etot) row = Etot - 1;
      const float* er = e + row * DD;
      #pragma unroll
      for (int kk = 0; kk < 4; ++kk) {
        e32[kk * 2]     = *(const float4*)&er[kk * 32 + lg * 8];
        e32[kk * 2 + 1] = *(const float4*)&er[kk * 32 + lg * 8 + 4];
      }
      #pragma unroll
      for (int z = 0; z < 4; ++z) {
        size_t erow = m0n + w * 16 + z * 4 + lg;
        if (erow >= (size_t)Etot) erow = Etot - 1;
        dnN[z] = dstI[erow]; snN[z] = srcI[erow]; posN[z] = posOf[erow];
      }
    }

    f32x4 acc[8] = {};
    #pragma unroll
    for (int kk = 0; kk < 4; ++kk) {
      #pragma unroll
      for (int tt = 0; tt < 8; ++tt) {
        bf16x8 bfv = *(const bf16x8*)&lds_wt[((tt * 4 + kk) * 64 + l) * 8];
        acc[tt] = __builtin_amdgcn_mfma_f32_16x16x32_bf16(af[kk], bfv, acc[tt], 0, 0, 0);
      }
    }

    #pragma unroll
    for (int tt = 0; tt < 8; ++tt) {
      int col = tt * 16 + lc;
      #pragma unroll
      for (int j = 0; j < 4; ++j)
        es[w][lg * 4 + j][col] = f2bf(acc[tt][j] + bCv[tt]);
    }
    asm volatile("s_waitcnt lgkmcnt(0)" ::: "memory");
    __builtin_amdgcn_sched_barrier(0);

    size_t m0 = (size_t)tile * 64;
    #pragma unroll
    for (int z = 0; z < 4; ++z) {
      size_t erow = m0 + w * 16 + z * 4 + lg;
      if (erow < (size_t)Etot) {
        int r = z * 4 + lg;
        bf16x8 cv = *(const bf16x8*)&es[w][r][lc * 8];
        bf16x8 o;
        #pragma unroll
        for (int j = 0; j < 8; ++j) {
          float v = bf2f(cv[j]) + bf2f(dv[z][j]) + bf2f(sv[z][j]);
          se[j] += v; qe[j] += v * v;
          o[j] = f2bf(v);
        }
        *(bf16x8*)&eijS[(size_t)pos[z] * DD + lc * 8] = o;
      }
    }
    __builtin_amdgcn_sched_barrier(0);
  }

  // per-wave stat partials (pE layout [GE*4][256])
  #pragma unroll
  for (int j = 0; j < 8; ++j) {
    se[j] += __shfl_xor(se[j], 16); se[j] += __shfl_xor(se[j], 32);
    qe[j] += __shfl_xor(qe[j], 16); qe[j] += __shfl_xor(qe[j], 32);
  }
  if (lg == 0) {
    size_t base = ((size_t)blockIdx.x * 4 + w) * 256;
    #pragma unroll
    for (int j = 0; j < 8; ++j) {
      pE[base + lc * 8 + j] = se[j];
      pE[base + 128 + lc * 8 + j] = qe[j];
    }
  }
}

// ---------------- gather helper ----------------
__device__ __forceinline__ void proc_edge(int id, bf16x8 ev, bf16x8 bv,
                                          const float* su, const float* hu,
                                          float* num, float* den,
                                          float* __restrict__ oute, int fi) {
  float va[8];
  #pragma unroll
  for (int j = 0; j < 8; ++j) {
    float v0 = bf2f(ev[j]);
    va[j] = fmaxf(0.f, v0 * su[j] + hu[j]);
    float g0 = 1.f / (1.f + __expf(-v0));
    num[j] += g0 * bf2f(bv[j]);
    den[j] += g0;
  }
  float4 oa, ob;
  oa.x = va[0]; oa.y = va[1]; oa.z = va[2]; oa.w = va[3];
  ob.x = va[4]; ob.y = va[5]; ob.z = va[6]; ob.w = va[7];
  *(float4*)&oute[(size_t)id * DD + fi * 8] = oa;
  *(float4*)&oute[(size_t)id * DD + fi * 8 + 4] = ob;
}

// ---------------- gather: 16/8/4-chain loops, node-level prefetch, bf16 x_pre --------------
__global__ __launch_bounds__(256) void k_gather(
    const int* __restrict__ off, const int* __restrict__ deg, const int* __restrict__ list,
    const int* __restrict__ srcS, const short* __restrict__ eijS, const short* __restrict__ Bxh,
    const short* __restrict__ Axh, const float* __restrict__ stE,
    short* __restrict__ outxh, float* __restrict__ oute,
    float* __restrict__ pX, int n) {
  int t = threadIdx.x;
  int w = t >> 6, l = t & 63;
  int qw = l >> 4, fi = l & 15;
  int waveId = blockIdx.x * 4 + w;
  const int nwaves = NB_G * 4;

  float su[8], hu[8];
  {
    float4 s0 = *(const float4*)&stE[fi * 8], s1 = *(const float4*)&stE[fi * 8 + 4];
    float4 h0 = *(const float4*)&stE[128 + fi * 8], h1 = *(const float4*)&stE[128 + fi * 8 + 4];
    su[0] = s0.x; su[1] = s0.y; su[2] = s0.z; su[3] = s0.w;
    su[4] = s1.x; su[5] = s1.y; su[6] = s1.z; su[7] = s1.w;
    hu[0] = h0.x; hu[1] = h0.y; hu[2] = h0.z; hu[3] = h0.w;
    hu[4] = h1.x; hu[5] = h1.y; hu[6] = h1.z; hu[7] = h1.w;
  }

  float sx[4] = {}, qx[4] = {};
  int c0 = fi * 8 + ((qw & 1) * 4);

  int startC = 0, dgC = 0;
  if (waveId < n) { startC = off[waveId]; dgC = deg[waveId]; }

  for (int node = waveId; node < n; node += nwaves) {
    int start = startC, dg = dgC;
    int nn = node + nwaves;
    if (nn < n) { startC = off[nn]; dgC = deg[nn]; }
    short4 ax = *(const short4*)&Axh[(size_t)node * DD + (qw < 2 ? c0 : fi * 8)];

    float num[8] = {}, den[8] = {};
    int k = qw;
    for (; k + 12 < dg; k += 16) {   // 4 chains/lane
      int p0 = start + k, p1 = p0 + 4, p2 = p0 + 8, p3 = p0 + 12;
      int id0 = list[p0], id1 = list[p1], id2 = list[p2], id3 = list[p3];
      int s0 = srcS[p0], s1 = srcS[p1], s2 = srcS[p2], s3 = srcS[p3];
      bf16x8 e0 = *(const bf16x8*)&eijS[(size_t)p0 * DD + fi * 8];
      bf16x8 e1 = *(const bf16x8*)&eijS[(size_t)p1 * DD + fi * 8];
      bf16x8 e2 = *(const bf16x8*)&eijS[(size_t)p2 * DD + fi * 8];
      bf16x8 e3 = *(const bf16x8*)&eijS[(size_t)p3 * DD + fi * 8];
      bf16x8 b0 = *(const bf16x8*)&Bxh[(size_t)s0 * DD + fi * 8];
      bf16x8 b1 = *(const bf16x8*)&Bxh[(size_t)s1 * DD + fi * 8];
      bf16x8 b2 = *(const bf16x8*)&Bxh[(size_t)s2 * DD + fi * 8];
      bf16x8 b3 = *(const bf16x8*)&Bxh[(size_t)s3 * DD + fi * 8];
      proc_edge(id0, e0, b0, su, hu, num, den, oute, fi);
      proc_edge(id1, e1, b1, su, hu, num, den, oute, fi);
      proc_edge(id2, e2, b2, su, hu, num, den, oute, fi);
      proc_edge(id3, e3, b3, su, hu, num, den, oute, fi);
    }
    for (; k + 4 < dg; k += 8) {     // 2 chains/lane
      int p0 = start + k, p1 = p0 + 4;
      int id0 = list[p0], id1 = list[p1];
      int s0 = srcS[p0], s1 = srcS[p1];
      bf16x8 e0 = *(const bf16x8*)&eijS[(size_t)p0 * DD + fi * 8];
      bf16x8 e1 = *(const bf16x8*)&eijS[(size_t)p1 * DD + fi * 8];
      bf16x8 b0 = *(const bf16x8*)&Bxh[(size_t)s0 * DD + fi * 8];
      bf16x8 b1 = *(const bf16x8*)&Bxh[(size_t)s1 * DD + fi * 8];
      proc_edge(id0, e0, b0, su, hu, num, den, oute, fi);
      proc_edge(id1, e1, b1, su, hu, num, den, oute, fi);
    }
    for (; k < dg; k += 4) {         // 1 chain
      int p0 = start + k;
      int id0 = list[p0];
      int s0 = srcS[p0];
      bf16x8 e0 = *(const bf16x8*)&eijS[(size_t)p0 * DD + fi * 8];
      bf16x8 b0 = *(const bf16x8*)&Bxh[(size_t)s0 * DD + fi * 8];
      proc_edge(id0, e0, b0, su, hu, num, den, oute, fi);
    }
    #pragma unroll
    for (int j = 0; j < 8; ++j) {
      num[j] += __shfl_xor(num[j], 16); num[j] += __shfl_xor(num[j], 32);
      den[j] += __shfl_xor(den[j], 16); den[j] += __shfl_xor(den[j], 32);
    }
    if (qw < 2) {
      short axa[4] = {ax.x, ax.y, ax.z, ax.w};
      short4 o;
      short ov[4];
      #pragma unroll
      for (int j = 0; j < 4; ++j) {
        int jj = qw * 4 + j;
        float aggr = num[jj] / (den[jj] + 1e-6f);
        float xp = bf2f(axa[j]) + aggr;
        ov[j] = f2bf(xp);
        sx[j] += xp; qx[j] += xp * xp;
      }
      o.x = ov[0]; o.y = ov[1]; o.z = ov[2]; o.w = ov[3];
      *(short4*)&outxh[(size_t)node * DD + c0] = o;
    }
  }

  __shared__ float lsX[4][128], lqX[4][128];
  if (qw < 2) {
    #pragma unroll
    for (int j = 0; j < 4; ++j) { lsX[w][fi * 8 + qw * 4 + j] = sx[j]; lqX[w][fi * 8 + qw * 4 + j] = qx[j]; }
  }
  __syncthreads();
  if (t < 128) {
    float a = lsX[0][t] + lsX[1][t] + lsX[2][t] + lsX[3][t];
    float b = lqX[0][t] + lqX[1][t] + lqX[2][t] + lqX[3][t];
    pX[(size_t)blockIdx.x * 256 + t] = a;
    pX[(size_t)blockIdx.x * 256 + 128 + t] = b;
  }
}

// reduce partials -> folded BN affine: stats[c]=scale, stats[128+c]=shift
__global__ __launch_bounds__(256) void k_reduce(const float* __restrict__ part, int nblk, float invcnt,
                                                const float* __restrict__ gamma, const float* __restrict__ beta,
                                                float* __restrict__ stats) {
  int c = blockIdx.x, t = threadIdx.x;
  float a = 0.f, b = 0.f;
  for (int k = t; k < nblk; k += 256) {
    a += part[(size_t)k * 256 + c];
    b += part[(size_t)k * 256 + 128 + c];
  }
  #pragma unroll
  for (int o = 32; o > 0; o >>= 1) { a += __shfl_down(a, o); b += __shfl_down(b, o); }
  __shared__ float ra[4], rb[4];
  int l = t & 63, w = t >> 6;
  if (l == 0) { ra[w] = a; rb[w] = b; }
  __syncthreads();
  if (t == 0) {
    a = ra[0] + ra[1] + ra[2] + ra[3];
    b = rb[0] + rb[1] + rb[2] + rb[3];
    float mean = a * invcnt;
    float var = b * invcnt - mean * mean;   // biased variance
    float istd = rsqrtf(var + 1e-5f);
    float scale = gamma[c] * istd;
    stats[c] = scale;
    stats[128 + c] = beta[c] - mean * scale;
  }
}

// ---------------- finalize x: bf16 x_pre -> BN+ReLU -> f32 out ----------------
__global__ __launch_bounds__(256) void k_xfinal(const short* __restrict__ vh, const float* __restrict__ st,
                                                float* __restrict__ out, size_t n8) {
  size_t i = (size_t)blockIdx.x * 256 + threadIdx.x;
  if (i >= n8) return;
  bf16x8 u = *(const bf16x8*)&vh[i * 8];
  int f0 = (int)((i * 8) & 127);
  float4 s0 = *(const float4*)&st[f0], s1 = *(const float4*)&st[f0 + 4];
  float4 h0 = *(const float4*)&st[128 + f0], h1 = *(const float4*)&st[128 + f0 + 4];
  float4 a, b;
  a.x = fmaxf(0.f, bf2f(u[0]) * s0.x + h0.x);
  a.y = fmaxf(0.f, bf2f(u[1]) * s0.y + h0.y);
  a.z = fmaxf(0.f, bf2f(u[2]) * s0.z + h0.z);
  a.w = fmaxf(0.f, bf2f(u[3]) * s0.w + h0.w);
  b.x = fmaxf(0.f, bf2f(u[4]) * s1.x + h1.x);
  b.y = fmaxf(0.f, bf2f(u[5]) * s1.y + h1.y);
  b.z = fmaxf(0.f, bf2f(u[6]) * s1.z + h1.z);
  b.w = fmaxf(0.f, bf2f(u[7]) * s1.w + h1.w);
  *(float4*)&out[i * 8] = a;
  *(float4*)&out[i * 8 + 4] = b;
}

extern "C" void kernel_launch(void* const* d_in, const int* in_sizes, int n_in,
                              void* d_out, int out_size, void* d_ws, size_t ws_size,
                              hipStream_t stream) {
  const float* x  = (const float*)d_in[0];
  const float* e  = (const float*)d_in[1];
  const int*   ei = (const int*)d_in[2];
  const float* WA = (const float*)d_in[3];  const float* bA = (const float*)d_in[4];
  const float* WB = (const float*)d_in[5];  const float* bB = (const float*)d_in[6];
  const float* WC = (const float*)d_in[7];  const float* bC = (const float*)d_in[8];
  const float* WD = (const float*)d_in[9];  const float* bD = (const float*)d_in[10];
  const float* WE = (const float*)d_in[11]; const float* bE = (const float*)d_in[12];
  const float* gx = (const float*)d_in[13]; const float* bx = (const float*)d_in[14];
  const float* ge = (const float*)d_in[15]; const float* be = (const float*)d_in[16];

  int N = in_sizes[0] / DD;
  int E = in_sizes[2] / 2;
  const int* srcI = ei;       // edge_index[0]
  const int* dstI = ei + E;   // edge_index[1]

  float* outx = (float*)d_out;
  float* oute = (float*)d_out + (size_t)N * DD;

  int ntilesE = (E + 63) / 64;

  char* wp = (char*)d_ws;
  auto alloc = [&](size_t sz) { char* p = wp; wp += (sz + 255) & ~(size_t)255; return p; };
  short* Axh    = (short*)alloc((size_t)N * DD * 2);
  short* Bxh    = (short*)alloc((size_t)N * DD * 2);
  short* Dxh    = (short*)alloc((size_t)N * DD * 2);
  short* Exh    = (short*)alloc((size_t)N * DD * 2);
  short* eijS   = (short*)alloc((size_t)E * DD * 2);
  short* outxh  = (short*)alloc((size_t)N * DD * 2);
  int*   deg    = (int*)alloc((size_t)N * 4);
  int*   off    = (int*)alloc((size_t)N * 4);
  int*   cursor = (int*)alloc((size_t)N * 4);
  int*   totals = (int*)alloc(1024);
  int*   boff   = (int*)alloc(1024);
  int*   list   = (int*)alloc((size_t)E * 4);
  int*   srcS   = (int*)alloc((size_t)E * 4);
  int*   posOf  = (int*)alloc((size_t)E * 4);
  float* pE     = (float*)alloc((size_t)GE * 4 * 256 * 4);   // per-wave partials
  float* pX     = (float*)alloc((size_t)NB_G * 256 * 4);
  float* statsE = (float*)alloc(1024);
  float* statsX = (float*)alloc(1024);
  short* WtA    = (short*)alloc((size_t)DD * DD * 2);
  short* WtB    = (short*)alloc((size_t)DD * DD * 2);
  short* WtC    = (short*)alloc((size_t)DD * DD * 2);
  short* WtD    = (short*)alloc((size_t)DD * DD * 2);
  short* WtE    = (short*)alloc((size_t)DD * DD * 2);
  (void)ws_size; (void)n_in; (void)out_size;

  int nsb = (N + 255) / 256;

  k_prep<<<5 + nsb, 256, 0, stream>>>(WA, WB, WC, WD, WE, WtA, WtB, WtC, WtD, WtE, deg, N);
  k_hist<<<(E + 255) / 256, 256, 0, stream>>>(dstI, deg, E);
  k_scan1<<<nsb, 256, 0, stream>>>(deg, off, totals, N);
  k_scan2<<<1, 256, 0, stream>>>(totals, boff, nsb);
  k_scan3<<<nsb, 256, 0, stream>>>(off, boff, cursor, N);
  k_fill<<<(E + 255) / 256, 256, 0, stream>>>(dstI, srcI, cursor, list, srcS, posOf, E);

  k_nodegemm<<<(N + 63) / 64, 256, 0, stream>>>(x, WtA, bA, WtB, bB, WtD, bD, WtE, bE,
                                                Axh, Bxh, Dxh, Exh, N);
  k_edge<<<GE, 256, 0, stream>>>(e, WtC, bC, srcI, dstI, posOf, Dxh, Exh, eijS, pE, E, ntilesE);
  k_reduce<<<128, 256, 0, stream>>>(pE, GE * 4, 1.0f / (float)E, ge, be, statsE);

  k_gather<<<NB_G, 256, 0, stream>>>(off, deg, list, srcS, eijS, Bxh, Axh, statsE,
                                     outxh, oute, pX, N);
  k_reduce<<<128, 256, 0, stream>>>(pX, NB_G, 1.0f / (float)N, gx, bx, statsX);
  k_xfinal<<<(int)(((size_t)N * DD / 8 + 255) / 256), 256, 0, stream>>>(outxh, statsX, outx, (size_t)N * DD / 8);
}